// Round 4
// baseline (196.921 us; speedup 1.0000x reference)
//
#include <hip/hip_runtime.h>
#include <math.h>

#define L_TOK 16
#define DMODEL 1024
#define NHEAD 16
#define DHEAD 64
#define NBLK 1024
#define BSZ 16
#define START_POS_C 16368
#define TTOT 16384
#define SPLITS 128
#define KSPLIT 16
#define QSCALE (0.125f * 1.4426950408889634f)   // 1/sqrt(64) * log2(e)

// workspace offsets, in floats (layout unchanged — 12.4 MB proven scale)
#define OFF_QKVP 0                                          // 16*16*3072 = 786432
#define OFF_QW   (OFF_QKVP + KSPLIT * L_TOK * 3 * DMODEL)   // 786432
#define OFF_ACC  (OFF_QW + NHEAD * L_TOK * DHEAD)           // 802816
#define OFF_M    (OFF_ACC + NHEAD * SPLITS * L_TOK * DHEAD) // 2899968
#define OFF_SE   (OFF_M + NHEAD * SPLITS * L_TOK)           // 2932736
#define OFF_ATTN (OFF_SE + NHEAD * SPLITS * L_TOK)          // 2965504
#define OFF_PROJP (OFF_ATTN + L_TOK * DMODEL)               // 2981888

typedef _Float16 half4_t __attribute__((ext_vector_type(4)));
typedef _Float16 half8_t __attribute__((ext_vector_type(8)));
typedef float float4v __attribute__((ext_vector_type(4)));

union H8 { _Float16 h[8]; half8_t v; };
union H4 { _Float16 h[4]; half4_t v; };

// LDS-DMA: 64 lanes x 16B -> lds_base + lane*16 (linear dest; per-lane source).
#define LDS_DMA16(gsrc, ldst)                                                        \
    __builtin_amdgcn_global_load_lds(                                                \
        (const __attribute__((address_space(1))) void*)(gsrc),                       \
        (__attribute__((address_space(3))) void*)(ldst), 16, 0, 0)

// ---------------------------------------------------------------------------
// Split-K partial GEMM (round-2 proven, unchanged).
// ---------------------------------------------------------------------------
__device__ __forceinline__ void load_batch(float* buf, const float* Wp, int bk, int ncols) {
#pragma unroll
    for (int i = 0; i < 16; ++i) buf[i] = Wp[(size_t)(bk + i) * ncols];
}

__device__ __forceinline__ void fma_batch(float4v* acc_, const float* buf,
                                          const float* sxT, int bk) {
#pragma unroll
    for (int i = 0; i < 16; ++i) {
        const float wv_ = buf[i];
        const float4v* xp = (const float4v*)&sxT[(bk + i) * 20];
        float4v xa = xp[0], xb = xp[1], xc = xp[2], xd = xp[3];
        acc_[0] += xa * wv_;
        acc_[1] += xb * wv_;
        acc_[2] += xc * wv_;
        acc_[3] += xd * wv_;
    }
}

__global__ __launch_bounds__(256) void gemm_part(const float* __restrict__ x,
                                                 const float* __restrict__ W,
                                                 float* __restrict__ part,
                                                 int ncols) {
    const int col = blockIdx.x * 256 + threadIdx.x;
    const int k0 = blockIdx.y * (DMODEL / KSPLIT);   // 64 ks per block

    __shared__ __align__(16) float sxT[64 * 20];     // [k][l], padded row = 80B
#pragma unroll
    for (int i = threadIdx.x; i < 64 * 16; i += 256) {
        int k = i & 63, l = i >> 6;
        sxT[k * 20 + l] = x[(size_t)l * DMODEL + k0 + k];
    }

    const float* Wp = W + (size_t)k0 * ncols + col;
    float wa[16], wb[16];
    load_batch(wa, Wp, 0, ncols);
    load_batch(wb, Wp, 16, ncols);
    __builtin_amdgcn_sched_barrier(0);
    __syncthreads();

    float4v acc_[4];
#pragma unroll
    for (int g = 0; g < 4; ++g) acc_[g] = (float4v){0.f, 0.f, 0.f, 0.f};

    fma_batch(acc_, wa, sxT, 0);
    load_batch(wa, Wp, 32, ncols);
    __builtin_amdgcn_sched_barrier(0);
    fma_batch(acc_, wb, sxT, 16);
    load_batch(wb, Wp, 48, ncols);
    __builtin_amdgcn_sched_barrier(0);
    fma_batch(acc_, wa, sxT, 32);
    fma_batch(acc_, wb, sxT, 48);

    const size_t base = ((size_t)blockIdx.y * L_TOK) * ncols + col;
#pragma unroll
    for (int g = 0; g < 4; ++g)
#pragma unroll
        for (int j = 0; j < 4; ++j)
            part[base + (size_t)(4 * g + j) * ncols] = acc_[g][j];
}

// ---------------------------------------------------------------------------
// Reduce split-K partials of QKV, add bias, scatter (unchanged from r3).
// ---------------------------------------------------------------------------
__global__ __launch_bounds__(256) void qkv_reduce_scatter(const float* __restrict__ part,
                                                          const float* __restrict__ b_attn,
                                                          const int* __restrict__ block_ids,
                                                          float* __restrict__ qws,
                                                          float* __restrict__ kpool,
                                                          float* __restrict__ vpool) {
    int tid = blockIdx.x * 256 + threadIdx.x;
    int n = tid % (3 * DMODEL);
    int l = tid / (3 * DMODEL);
    float p[KSPLIT];
#pragma unroll
    for (int kb = 0; kb < KSPLIT; ++kb)
        p[kb] = part[((size_t)kb * L_TOK + l) * (3 * DMODEL) + n];
    float s = b_attn[n];
#pragma unroll
    for (int st = 1; st < KSPLIT; st <<= 1)
#pragma unroll
        for (int i = 0; i < KSPLIT; i += 2 * st) p[i] += p[i + st];
    s += p[0];
    int sec = n >> 10;
    int m = n & (DMODEL - 1);
    int h = m >> 6;
    int dd = m & 63;
    if (sec == 0) {
        qws[(h * L_TOK + l) * DHEAD + dd] = s * QSCALE;
    } else {
        int pos = START_POS_C + l;
        int blk = block_ids[pos >> 4];
        int off = pos & 15;
        size_t idx = (((size_t)blk * BSZ + off) * NHEAD + h) * DHEAD + dd;
        if (sec == 1) kpool[idx] = s;
        else          vpool[idx] = s;
    }
}

// ---------------------------------------------------------------------------
// paged_attn v9: CONTIGUOUS streaming. Grid = (2 head-halves, 128 splits);
// block = 8 heads x 128 tokens, 4 waves x 2 heads. Per 16-token tile the
// block DMAs 2KB-contiguous-per-token runs (8x longer than the old 256B comb
// — the r0-r3 invariant that pinned HBM at 1.45 TB/s). Tiles double-buffered
// in 128KB LDS; raw s_barrier + counted vmcnt(16) keeps next tile streaming
// under compute. Online softmax across tiles; no cross-wave merge.
// 16B-slot XOR swizzle (slot ^ (tok&7)) applied to BOTH DMA source and LDS
// reads -> K b128 frags and V b32 gathers are 2-way (free).
// ---------------------------------------------------------------------------
__device__ __forceinline__ void stage_tile(const float* __restrict__ kpool,
                                           const float* __restrict__ vpool,
                                           float* kb, float* vb, int blk,
                                           int w, int lane, int hgrp) {
    const float* gk = kpool + (size_t)blk * 16384;   // blk * 16 tok * 1024 fl
    const float* gv = vpool + (size_t)blk * 16384;
#pragma unroll
    for (int i = 0; i < 4; ++i) {
        const int tok = 4 * w + i;
        const int lx = lane ^ (tok & 7);             // source pre-swizzle
#pragma unroll
        for (int part = 0; part < 2; ++part) {
            const size_t go = (size_t)tok * 1024 + hgrp * 512 + part * 256 + lx * 4;
            LDS_DMA16(gk + go, kb + tok * 512 + part * 256);
            LDS_DMA16(gv + go, vb + tok * 512 + part * 256);
        }
    }
}

__device__ __forceinline__ void attn_tile(const float* kt, const float* vt,
                                          int hh, half8_t qlo, half8_t qhi,
                                          float4v* acc, float& m_run, float& se_run,
                                          int tb, int c, int quad) {
    const int keyc = c & 7;
    const int hb = hh << 4;                          // head base, 16B-slot units
    const float* krow = kt + c * 512;
    float4v a0 = *(const float4v*)&krow[(((hb | (2 * quad)) ^ keyc) << 2)];
    float4v a1 = *(const float4v*)&krow[(((hb | (2 * quad + 1)) ^ keyc) << 2)];
    float4v a2 = *(const float4v*)&krow[(((hb | (2 * quad + 8)) ^ keyc) << 2)];
    float4v a3 = *(const float4v*)&krow[(((hb | (2 * quad + 9)) ^ keyc) << 2)];
    H8 ka, kb;
    ka.h[0]=(_Float16)a0[0]; ka.h[1]=(_Float16)a0[1]; ka.h[2]=(_Float16)a0[2]; ka.h[3]=(_Float16)a0[3];
    ka.h[4]=(_Float16)a1[0]; ka.h[5]=(_Float16)a1[1]; ka.h[6]=(_Float16)a1[2]; ka.h[7]=(_Float16)a1[3];
    kb.h[0]=(_Float16)a2[0]; kb.h[1]=(_Float16)a2[1]; kb.h[2]=(_Float16)a2[2]; kb.h[3]=(_Float16)a2[3];
    kb.h[4]=(_Float16)a3[0]; kb.h[5]=(_Float16)a3[1]; kb.h[6]=(_Float16)a3[2]; kb.h[7]=(_Float16)a3[3];
    const float4v z4 = {0.f, 0.f, 0.f, 0.f};
    float4v st = __builtin_amdgcn_mfma_f32_16x16x32_f16(ka.v, qlo, z4, 0, 0, 0);
    st = __builtin_amdgcn_mfma_f32_16x16x32_f16(kb.v, qhi, st, 0, 0, 0);

    if (tb + 15 > START_POS_C) {
#pragma unroll
        for (int r = 0; r < 4; ++r)
            if (tb + 4 * quad + r > START_POS_C + c) st[r] = -INFINITY;
    }

    float tm = fmaxf(fmaxf(st[0], st[1]), fmaxf(st[2], st[3]));
    tm = fmaxf(tm, __shfl_xor(tm, 16, 64));
    tm = fmaxf(tm, __shfl_xor(tm, 32, 64));
    const float m_new = fmaxf(m_run, tm);
    const float fac = exp2f(m_run - m_new);          // m_run=-inf first tile -> 0
    H4 pa;
    pa.h[0]=(_Float16)exp2f(st[0]-m_new); pa.h[1]=(_Float16)exp2f(st[1]-m_new);
    pa.h[2]=(_Float16)exp2f(st[2]-m_new); pa.h[3]=(_Float16)exp2f(st[3]-m_new);
    float tsum = ((float)pa.h[0] + (float)pa.h[1]) + ((float)pa.h[2] + (float)pa.h[3]);
    tsum += __shfl_xor(tsum, 16, 64);
    tsum += __shfl_xor(tsum, 32, 64);
    se_run = se_run * fac + tsum;
    m_run = m_new;
    // per-row (query 4*quad+r) rescale factors, fetched from lanes c=4q+r
    float4v fv;
    fv[0] = __shfl(fac, 4 * quad + 0, 64);
    fv[1] = __shfl(fac, 4 * quad + 1, 64);
    fv[2] = __shfl(fac, 4 * quad + 2, 64);
    fv[3] = __shfl(fac, 4 * quad + 3, 64);
#pragma unroll
    for (int ndv = 0; ndv < 4; ++ndv) acc[ndv] *= fv;
#pragma unroll
    for (int ndv = 0; ndv < 4; ++ndv) {
        H4 bf;
#pragma unroll
        for (int j = 0; j < 4; ++j) {
            const int tokr = 4 * quad + j;
            const int slot = (hb | (4 * ndv + (c >> 2))) ^ (tokr & 7);
            bf.h[j] = (_Float16)vt[tokr * 512 + (slot << 2) + (c & 3)];
        }
        acc[ndv] = __builtin_amdgcn_mfma_f32_16x16x16f16(pa.v, bf.v, acc[ndv], 0, 0, 0);
    }
}

__global__ __launch_bounds__(256, 1) void paged_attn(const float* __restrict__ kpool,
                                                     const float* __restrict__ vpool,
                                                     const int* __restrict__ block_ids,
                                                     const float* __restrict__ qws,
                                                     float* __restrict__ accws,
                                                     float* __restrict__ m_arr,
                                                     float* __restrict__ se_arr) {
    const int hgrp = blockIdx.x;                     // head half: 0-7 / 8-15
    const int s = blockIdx.y;
    const int tid = threadIdx.x;
    const int w = tid >> 6;
    const int lane = tid & 63;
    const int c = lane & 15;
    const int quad = lane >> 4;

    __shared__ __align__(16) float kbuf[2][8192];    // [dbuf][tok 16][8h*64]
    __shared__ __align__(16) float vbuf[2][8192];    // total 128 KB

    int blks[8];
#pragma unroll
    for (int t = 0; t < 8; ++t) blks[t] = block_ids[s * 8 + t];

    // Q for this wave's two heads (h0 = hgrp*8 + 2w, h0+1)
    const int h0 = hgrp * 8 + 2 * w;
    H8 qA0, qA1, qB0, qB1;
    {
        const float* qr = qws + ((size_t)(h0 * L_TOK + c)) * DHEAD + quad * 8;
        float4 x0 = *(const float4*)(qr),        x1 = *(const float4*)(qr + 4);
        float4 x2 = *(const float4*)(qr + 32),   x3 = *(const float4*)(qr + 36);
        float4 y0 = *(const float4*)(qr + 1024), y1 = *(const float4*)(qr + 1028);
        float4 y2 = *(const float4*)(qr + 1056), y3 = *(const float4*)(qr + 1060);
        qA0.h[0]=(_Float16)x0.x; qA0.h[1]=(_Float16)x0.y; qA0.h[2]=(_Float16)x0.z; qA0.h[3]=(_Float16)x0.w;
        qA0.h[4]=(_Float16)x1.x; qA0.h[5]=(_Float16)x1.y; qA0.h[6]=(_Float16)x1.z; qA0.h[7]=(_Float16)x1.w;
        qA1.h[0]=(_Float16)x2.x; qA1.h[1]=(_Float16)x2.y; qA1.h[2]=(_Float16)x2.z; qA1.h[3]=(_Float16)x2.w;
        qA1.h[4]=(_Float16)x3.x; qA1.h[5]=(_Float16)x3.y; qA1.h[6]=(_Float16)x3.z; qA1.h[7]=(_Float16)x3.w;
        qB0.h[0]=(_Float16)y0.x; qB0.h[1]=(_Float16)y0.y; qB0.h[2]=(_Float16)y0.z; qB0.h[3]=(_Float16)y0.w;
        qB0.h[4]=(_Float16)y1.x; qB0.h[5]=(_Float16)y1.y; qB0.h[6]=(_Float16)y1.z; qB0.h[7]=(_Float16)y1.w;
        qB1.h[0]=(_Float16)y2.x; qB1.h[1]=(_Float16)y2.y; qB1.h[2]=(_Float16)y2.z; qB1.h[3]=(_Float16)y2.w;
        qB1.h[4]=(_Float16)y3.x; qB1.h[5]=(_Float16)y3.y; qB1.h[6]=(_Float16)y3.z; qB1.h[7]=(_Float16)y3.w;
    }

    stage_tile(kpool, vpool, kbuf[0], vbuf[0], blks[0], w, lane, hgrp);

    float4v accA[4], accB[4];
#pragma unroll
    for (int i = 0; i < 4; ++i) {
        accA[i] = (float4v){0.f, 0.f, 0.f, 0.f};
        accB[i] = (float4v){0.f, 0.f, 0.f, 0.f};
    }
    float mA = -INFINITY, seA = 0.f, mB = -INFINITY, seB = 0.f;

    float* kc = kbuf[0]; float* vc = vbuf[0];
    float* kn = kbuf[1]; float* vn = vbuf[1];

    for (int t = 0; t < 8; ++t) {
        if (t < 7) {
            stage_tile(kpool, vpool, kn, vn, blks[t + 1], w, lane, hgrp);
            asm volatile("s_waitcnt vmcnt(16)" ::: "memory");   // tile t retired; t+1 in flight
        } else {
            asm volatile("s_waitcnt vmcnt(0)" ::: "memory");
        }
        __builtin_amdgcn_sched_barrier(0);
        __builtin_amdgcn_s_barrier();                // all waves' tile-t writes visible

        const int tb = s * 128 + t * 16;
        attn_tile(kc, vc, 2 * w,     qA0.v, qA1.v, accA, mA, seA, tb, c, quad);
        attn_tile(kc, vc, 2 * w + 1, qB0.v, qB1.v, accB, mB, seB, tb, c, quad);

        __builtin_amdgcn_s_barrier();                // reads done before buf reuse
        float* tk = kc; kc = kn; kn = tk;
        float* tv = vc; vc = vn; vn = tv;
    }

    // epilogue: this wave owns (h0,s) and (h0+1,s) fully
    const size_t obA = ((size_t)(h0 * SPLITS + s) * L_TOK) * DHEAD;
    const size_t obB = ((size_t)((h0 + 1) * SPLITS + s) * L_TOK) * DHEAD;
#pragma unroll
    for (int ndv = 0; ndv < 4; ++ndv)
#pragma unroll
        for (int r = 0; r < 4; ++r) {
            accws[obA + (size_t)(4 * quad + r) * DHEAD + 16 * ndv + c] = accA[ndv][r];
            accws[obB + (size_t)(4 * quad + r) * DHEAD + 16 * ndv + c] = accB[ndv][r];
        }
    if (quad == 0) {
        const size_t mbA = (size_t)(h0 * SPLITS + s) * L_TOK + c;
        const size_t mbB = (size_t)((h0 + 1) * SPLITS + s) * L_TOK + c;
        m_arr[mbA] = mA; se_arr[mbA] = seA;
        m_arr[mbB] = mB; se_arr[mbB] = seB;
    }
}

// ---------------------------------------------------------------------------
// Combine split partials (two-pass, independent loads — unchanged).
// ---------------------------------------------------------------------------
__global__ __launch_bounds__(256) void combine(const float* __restrict__ accws,
                                               const float* __restrict__ m_arr,
                                               const float* __restrict__ se_arr,
                                               float* __restrict__ attnws) {
    const int h = blockIdx.x >> 4;
    const int l = blockIdx.x & 15;
    const int w = threadIdx.x >> 6;
    const int lane = threadIdx.x & 63;
    __shared__ float sm[4], sse[4], sacc[4][64];

    const size_t base = (size_t)h * SPLITS * L_TOK + l;

    float mreg[SPLITS / 4];
#pragma unroll
    for (int i = 0; i < SPLITS / 4; ++i)
        mreg[i] = m_arr[base + (size_t)(w + 4 * i) * L_TOK];
    float M = -INFINITY;
#pragma unroll
    for (int i = 0; i < SPLITS / 4; ++i) M = fmaxf(M, mreg[i]);

    float num = 0.f, den = 0.f;
#pragma unroll
    for (int i = 0; i < SPLITS / 4; ++i) {
        const size_t idx = base + (size_t)(w + 4 * i) * L_TOK;
        const float wgt = exp2f(mreg[i] - M);
        num = fmaf(wgt, accws[idx * DHEAD + lane], num);
        den = fmaf(wgt, se_arr[idx], den);
    }

    if (lane == 0) { sm[w] = M; sse[w] = den; }
    sacc[w][lane] = num;
    __syncthreads();
    if (w == 0) {
        const float M0 = fmaxf(fmaxf(sm[0], sm[1]), fmaxf(sm[2], sm[3]));
        float nn = 0.f, dd = 0.f;
#pragma unroll
        for (int i = 0; i < 4; ++i) {
            const float wgt = exp2f(sm[i] - M0);
            nn = fmaf(wgt, sacc[i][lane], nn);
            dd = fmaf(wgt, sse[i], dd);
        }
        attnws[(size_t)l * DMODEL + h * DHEAD + lane] = nn / dd;
    }
}

// ---------------------------------------------------------------------------
// Reduce split-K partials of final projection + bias -> d_out (unchanged).
// ---------------------------------------------------------------------------
__global__ __launch_bounds__(256) void proj_reduce(const float* __restrict__ part,
                                                   const float* __restrict__ bias,
                                                   float* __restrict__ out) {
    int tid = blockIdx.x * 256 + threadIdx.x;   // < 16384
    int n = tid & (DMODEL - 1);
    int l = tid >> 10;
    float p[KSPLIT];
#pragma unroll
    for (int kb = 0; kb < KSPLIT; ++kb)
        p[kb] = part[((size_t)kb * L_TOK + l) * DMODEL + n];
#pragma unroll
    for (int st = 1; st < KSPLIT; st <<= 1)
#pragma unroll
        for (int i = 0; i < KSPLIT; i += 2 * st) p[i] += p[i + st];
    out[tid] = bias[n] + p[0];
}

extern "C" void kernel_launch(void* const* d_in, const int* in_sizes, int n_in,
                              void* d_out, int out_size, void* d_ws, size_t ws_size,
                              hipStream_t stream) {
    const float* x       = (const float*)d_in[0];
    float* kpool         = (float*)d_in[1];
    float* vpool         = (float*)d_in[2];
    const float* W_attn  = (const float*)d_in[3];
    const float* b_attn  = (const float*)d_in[4];
    const float* W_proj  = (const float*)d_in[5];
    const float* b_proj  = (const float*)d_in[6];
    const int* block_ids = (const int*)d_in[7];
    float* ws  = (float*)d_ws;
    float* out = (float*)d_out;

    // 1) QKV projection (split-K partials)
    gemm_part<<<dim3(12, KSPLIT), 256, 0, stream>>>(x, W_attn, ws + OFF_QKVP, 3 * DMODEL);
    // 2) reduce + bias; q -> ws (scaled), new k/v -> pools (paged write)
    qkv_reduce_scatter<<<192, 256, 0, stream>>>(ws + OFF_QKVP, b_attn, block_ids,
                                                ws + OFF_QW, kpool, vpool);
    // 3) flash-decode attention (contiguous-streaming, double-buffered tiles)
    paged_attn<<<dim3(2, SPLITS), 256, 0, stream>>>(kpool, vpool, block_ids,
                                                    ws + OFF_QW, ws + OFF_ACC,
                                                    ws + OFF_M, ws + OFF_SE);
    // 4) combine splits
    combine<<<NHEAD * L_TOK, 256, 0, stream>>>(ws + OFF_ACC, ws + OFF_M, ws + OFF_SE,
                                               ws + OFF_ATTN);
    // 5) output projection (split-K partials)
    gemm_part<<<dim3(4, KSPLIT), 256, 0, stream>>>(ws + OFF_ATTN, W_proj, ws + OFF_PROJP, DMODEL);
    // 6) reduce + bias -> d_out
    proj_reduce<<<64, 256, 0, stream>>>(ws + OFF_PROJP, b_proj, out);
}